// Round 8
// baseline (464.768 us; speedup 1.0000x reference)
//
#include <hip/hip_runtime.h>
#include <hip/hip_bf16.h>

#define N 8192
#define D 64

typedef __attribute__((ext_vector_type(8))) short bf16x8;
typedef __attribute__((ext_vector_type(4))) float f32x4;

__device__ inline unsigned short f2b(float f) {
    __hip_bfloat16 h = __float2bfloat16(f);
    return __builtin_bit_cast(unsigned short, h);
}

__device__ inline float exp2fast(float x) {
#if __has_builtin(__builtin_amdgcn_exp2f)
    return __builtin_amdgcn_exp2f(x);   // v_exp_f32 (D = 2^S0)
#else
    return exp2f(x);
#endif
}

// Kernel 1: X (fp32) -> Xb (bf16); sq[i] = ||x_i||^2; per-block column partials Vp.
__global__ __launch_bounds__(256) void gk_prep(const float4* __restrict__ X4,
                                               ushort4* __restrict__ Xb4,
                                               float* __restrict__ sq,
                                               float4* __restrict__ Vp4) {
    __shared__ float4 sm[256];
    const int tid = threadIdx.x;
    const int g = blockIdx.x * 256 + tid;   // float4 index
    float4 v = X4[g];
    ushort4 b;
    b.x = f2b(v.x); b.y = f2b(v.y); b.z = f2b(v.z); b.w = f2b(v.w);
    Xb4[g] = b;
    float ss = v.x * v.x + v.y * v.y + v.z * v.z + v.w * v.w;
    ss += __shfl_xor(ss, 8, 16);
    ss += __shfl_xor(ss, 4, 16);
    ss += __shfl_xor(ss, 2, 16);
    ss += __shfl_xor(ss, 1, 16);
    if ((tid & 15) == 0) sq[g >> 4] = ss;
    sm[tid] = v;
    __syncthreads();
#pragma unroll
    for (int off = 128; off >= 16; off >>= 1) {
        if (tid < off) {
            float4 o = sm[tid + off];
            float4 m = sm[tid];
            m.x += o.x; m.y += o.y; m.z += o.z; m.w += o.w;
            sm[tid] = m;
        }
        __syncthreads();
    }
    if (tid < 16) Vp4[blockIdx.x * 16 + tid] = sm[tid];   // [512][64] floats
}

// Kernel 2: S=sum(sq); V[c]=sum Vp; mean = 2S/N - 2||V||^2/N^2; sc = 1/(2*mean).
// u[i] = sq[i]*sc*log2(e), scal[1] = 2*sc*log2(e). Identity proven (absmax
// bit-identical since R3).
__global__ __launch_bounds__(256) void gk_finalize(const float* __restrict__ sq,
                                                   const float* __restrict__ Vp,
                                                   float* __restrict__ scal,
                                                   float4* __restrict__ u4) {
    __shared__ float red[256];
    const int tid = threadIdx.x;
    float s = 0.f;
    for (int r = tid; r < N; r += 256) s += sq[r];
    red[tid] = s;
    __syncthreads();
    for (int off = 128; off > 0; off >>= 1) {
        if (tid < off) red[tid] += red[tid + off];
        __syncthreads();
    }
    const float S = red[0];
    __syncthreads();
    const int c = tid & 63, p = tid >> 6;
    float v = 0.f;
    for (int r = p; r < 512; r += 4) v += Vp[r * 64 + c];
    red[tid] = v;
    __syncthreads();
    if (tid < 128) red[tid] += red[tid + 128];
    __syncthreads();
    if (tid < 64) red[tid] += red[tid + 64];
    __syncthreads();
    float vv = (tid < 64) ? red[tid] * red[tid] : 0.f;
    __syncthreads();
    red[tid] = vv;
    __syncthreads();
    for (int off = 128; off > 0; off >>= 1) {
        if (tid < off) red[tid] += red[tid + off];
        __syncthreads();
    }
    if (tid == 0) {
        const float Vsq = red[0];
        const float fN = (float)N;
        const float mean = 2.f * S / fN - 2.f * Vsq / (fN * fN);
        const float sc = 1.f / (2.f * mean);          // ALPHA = 1.0
        const float L2E = 1.4426950408889634f;
        scal[0] = sc;
        scal[1] = 2.f * sc * L2E;                     // k2
        red[0] = sc * L2E;                            // broadcast uc
    }
    __syncthreads();
    const float uc = red[0];
    const float4* sqv = reinterpret_cast<const float4*>(sq);
    for (int r = tid; r < N / 4; r += 256) {
        float4 q = sqv[r];
        float4 o;
        o.x = q.x * uc; o.y = q.y * uc; o.z = q.z * uc; o.w = q.w * uc;
        u4[r] = o;
    }
}

// Kernel 3: main — R7 structure, DIAGNOSTIC 3x INTERNAL REPEAT.
// [R7 lesson] 4 orthogonal theories (store shape x3, occupancy) all null within
// +/-15us cross-round noise; main's own counters never visible (every instance
// < the ~50 fill dispatches at 160-172us). This round: run the body 3x in ONE
// dispatch (idempotent — same values to same addresses; memory clobber between
// reps blocks load-CSE/store-merge). If main is slow (W1: ~95-130us) the 3x
// dispatch lands at 285-390us -> top-5 row WITH MfmaUtil/VALUBusy/FETCH/WRITE.
// If main is already at write-roofline (W2: ~45-60us) total rises only ~100us
// and W2 is confirmed by arithmetic. Either way the deadlock breaks.
__global__ __launch_bounds__(256, 6) void gk_main(const unsigned short* __restrict__ Xb,
                                                  const float* __restrict__ u,
                                                  const float* __restrict__ scal,
                                                  float* __restrict__ out) {
    const int lane = threadIdx.x & 63;
    const int wave = threadIdx.x >> 6;
    const int i0 = blockIdx.x * 64 + wave * 16;
    const int j0 = blockIdx.y * 128;
    const int m = lane & 15;
    const int q = lane >> 4;   // 0..3
    const float k2 = scal[1];

#pragma unroll 1
    for (int rep = 0; rep < 3; ++rep) {
        // A fragments: row i0+m, k = 8q..8q+7 (+32 for second chunk)
        const bf16x8* Arow = reinterpret_cast<const bf16x8*>(Xb + (i0 + m) * D + 8 * q);
        const bf16x8 a0 = Arow[0];
        const bf16x8 a1 = Arow[4];

        float ui[4];
#pragma unroll
        for (int r = 0; r < 4; ++r) ui[r] = u[i0 + 4 * q + r];

        const bf16x8* Bbase = reinterpret_cast<const bf16x8*>(Xb + (j0 + m) * D + 8 * q);
        const float* ucol = u + j0 + m;
        float* ob0 = out + (size_t)(i0 + 4 * q + 0) * N + j0 + m;
        float* ob1 = out + (size_t)(i0 + 4 * q + 1) * N + j0 + m;
        float* ob2 = out + (size_t)(i0 + 4 * q + 2) * N + j0 + m;
        float* ob3 = out + (size_t)(i0 + 4 * q + 3) * N + j0 + m;

#pragma unroll 2
        for (int t = 0; t < 8; ++t) {
            const bf16x8 b0 = Bbase[t * 16 * (D / 8)];       // +t*2048 bytes
            const bf16x8 b1 = Bbase[t * 16 * (D / 8) + 4];   // +32 elems (k-chunk 1)
            f32x4 acc = (f32x4){0.f, 0.f, 0.f, 0.f};
            acc = __builtin_amdgcn_mfma_f32_16x16x32_bf16(a0, b0, acc, 0, 0, 0);
            acc = __builtin_amdgcn_mfma_f32_16x16x32_bf16(a1, b1, acc, 0, 0, 0);
            const float uj = ucol[t * 16];
            const float p0 = fmaf(k2, acc[0], -(ui[0] + uj));
            const float p1 = fmaf(k2, acc[1], -(ui[1] + uj));
            const float p2 = fmaf(k2, acc[2], -(ui[2] + uj));
            const float p3 = fmaf(k2, acc[3], -(ui[3] + uj));
            ob0[t * 16] = exp2fast(fminf(p0, 0.f));
            ob1[t * 16] = exp2fast(fminf(p1, 0.f));
            ob2[t * 16] = exp2fast(fminf(p2, 0.f));
            ob3[t * 16] = exp2fast(fminf(p3, 0.f));
        }
        asm volatile("" ::: "memory");   // block CSE/store-merge across reps
    }
}

extern "C" void kernel_launch(void* const* d_in, const int* in_sizes, int n_in,
                              void* d_out, int out_size, void* d_ws, size_t ws_size,
                              hipStream_t stream) {
    const float* X = (const float*)d_in[0];
    float* out = (float*)d_out;

    char* ws = (char*)d_ws;
    unsigned short* Xb = (unsigned short*)ws;                       // 1 MiB
    float* sq = (float*)(ws + (1 << 20));                           // 32 KiB
    float* Vp = (float*)(ws + (1 << 20) + (32 << 10));              // 128 KiB
    float* u  = (float*)(ws + (1 << 20) + (160 << 10));             // 32 KiB
    float* scal = (float*)(ws + (1 << 20) + (192 << 10));           // scalars

    gk_prep<<<512, 256, 0, stream>>>((const float4*)X, (ushort4*)Xb, sq, (float4*)Vp);
    gk_finalize<<<1, 256, 0, stream>>>(sq, Vp, scal, (float4*)u);

    dim3 grid(N / 64, N / 128);   // x = row tiles, y = col tiles
    gk_main<<<grid, 256, 0, stream>>>(Xb, u, scal, out);
}